// Round 3
// baseline (119.683 us; speedup 1.0000x reference)
//
#include <hip/hip_runtime.h>

// Problem constants (from reference):
//   L=36, G=180, A=0.2, RO=2.5, RMAX=13, B=27, CELLS=27^3=19683
//   NRAD=8, NL=4 -> 16 masked (l,m) pairs, VCELL=0.008
#define G 180
#define NRAD 8
#define RO_F 2.5f
#define A_F 0.2f
#define VCELL_F 0.008f
#define CELLS 19683
#define SLABS 8
#define NATOMS 64

// ws layout:
//   float partials[NATOMS][SLABS][128]   (fully overwritten every call)
//   unsigned ctr[NATOMS]                 (atomicInc with wrap=7: self-
//     reinitializing from ANY start value -- 0xAA poison, 7 from previous
//     call, or garbage -- 8 increments always end at 7, exactly one block
//     sees old==6 as the last arrival)
#define CTR_OFF (NATOMS * SLABS * 128)

// lm ordering (matches coeff[:, MASK].reshape(-1)):
// 0:(0,0) 1:(1,-1) 2:(1,0) 3:(1,1) 4:(2,-2) 5:(2,-1) 6:(2,0) 7:(2,1) 8:(2,2)
// 9:(3,-3) 10:(3,-2) 11:(3,-1) 12:(3,0) 13:(3,1) 14:(3,2) 15:(3,3)

__global__ __launch_bounds__(256, 2) void proj_fused_kernel(
    const float* __restrict__ rho, const float* __restrict__ pos,
    const float* __restrict__ W, float* __restrict__ out,
    float* __restrict__ ws)
{
    const int atom = blockIdx.y;
    const int slab = blockIdx.x;
    const int tid  = threadIdx.x;
    const int lane = tid & 63;
    const int waveid = tid >> 6;

    const float px = pos[atom*3+0], py = pos[atom*3+1], pz = pos[atom*3+2];
    // cm = round(pos/A); dr = pos - A*cm   (A = 0.2 -> pos*5)
    const float cmx = rintf(px * 5.0f), cmy = rintf(py * 5.0f), cmz = rintf(pz * 5.0f);
    const float drx = px - A_F*cmx, dry = py - A_F*cmy, drz = pz - A_F*cmz;
    const int icx = (int)cmx - 13, icy = (int)cmy - 13, icz = (int)cmz - 13;

    float acc[128];
    #pragma unroll
    for (int j = 0; j < 128; ++j) acc[j] = 0.0f;

    for (int c = slab*256 + tid; c < CELLS; c += SLABS*256) {
        int i = c / 729;
        int rem = c - i*729;
        int j = rem / 27;
        int k = rem - j*27;
        // periodic wrap: i+icx in [-13, 193]
        int gx = i + icx; gx += (gx < 0) ? G : 0; gx -= (gx >= G) ? G : 0;
        int gy = j + icy; gy += (gy < 0) ? G : 0; gy -= (gy >= G) ? G : 0;
        int gz = k + icz; gz += (gz < 0) ? G : 0; gz -= (gz >= G) ? G : 0;
        float s = rho[(gx*G + gy)*G + gz];

        float x = (float)(i-13)*A_F - drx;
        float y = (float)(j-13)*A_F - dry;
        float z = (float)(k-13)*A_F - drz;
        float r2 = x*x + y*y + z*z;
        float inv = rsqrtf(fmaxf(r2, 1e-24f));
        float R = r2 * inv;                 // == sqrt(r2)
        if (R < RO_F) {
            float t = RO_F - R;
            float ux = x*inv, uy = y*inv, uz = z*inv;
            float uz2 = uz*uz;
            float ux2 = ux*ux, uy2 = uy*uy;
            // rho folded into the radial chain (p0 = s*r2*t^2), Y's are pure.
            float ys[16];
            ys[0]  = 0.28209479177f;
            ys[1]  = 0.48860251190f * uy;
            ys[2]  = 0.48860251190f * uz;
            ys[3]  = 0.48860251190f * ux;
            ys[4]  = 1.09254843059f * ux*uy;            // 2 * 0.54627 * ux uy
            ys[5]  = 1.09254843059f * uy*uz;
            ys[6]  = 0.31539156525f * (3.0f*uz2 - 1.0f);
            ys[7]  = 1.09254843059f * ux*uz;
            ys[8]  = 0.54627421530f * (ux2 - uy2);
            ys[9]  = 0.59004358993f * uy*(3.0f*ux2 - uy2);
            ys[10] = 2.89061144264f * ux*uy*uz;         // 2 * 1.44530572
            ys[11] = 0.45704579946f * uy*(5.0f*uz2 - 1.0f);
            ys[12] = 0.37317633259f * uz*(5.0f*uz2 - 3.0f);
            ys[13] = 0.45704579946f * ux*(5.0f*uz2 - 1.0f);
            ys[14] = 1.44530572132f * (ux2 - uy2)*uz;
            ys[15] = 0.59004358993f * ux*(ux2 - 3.0f*uy2);

            float p = s * r2 * t * t;       // s * phi_0
            #pragma unroll
            for (int n = 0; n < NRAD; ++n) {
                #pragma unroll
                for (int q = 0; q < 16; ++q)
                    acc[n*16+q] = fmaf(p, ys[q], acc[n*16+q]);
                p *= t;                     // phi_{n+1} = phi_n * (RO-R)
            }
        }
    }

    // Block reduction, no atomics:
    //  stage 1: per-wave LDS transpose (pad 33 -> conflict-free), each lane
    //           sums a 32-row half-column -> partial per (wave, half, col)
    //  stage 2: 8 partials per output idx gathered by tid<128
    __shared__ float red[4][64][33];      // ~33 KB
    __shared__ float stage[4][8][32];     // 4 KB
    __shared__ unsigned last_flag;
    const int col  = lane & 31;
    const int half = lane >> 5;
    #pragma unroll
    for (int cb = 0; cb < 4; ++cb) {
        __syncthreads();                  // WAR: previous chunk's reads done
        #pragma unroll
        for (int q = 0; q < 32; ++q)
            red[waveid][lane][q] = acc[cb*32 + q];
        __syncthreads();
        float csum = 0.0f;
        #pragma unroll
        for (int r = 0; r < 32; ++r)
            csum += red[waveid][half*32 + r][col];
        stage[cb][waveid*2 + half][col] = csum;
    }
    __syncthreads();
    if (tid < 128) {
        const int cb = tid >> 5, c2 = tid & 31;
        float sum = 0.0f;
        #pragma unroll
        for (int r = 0; r < 8; ++r)
            sum += stage[cb][r][c2];
        ws[(atom*SLABS + slab)*128 + tid] = sum;
    }

    // --- last-block-per-atom finalize (stream-k style) ---
    __threadfence();                      // release: partials device-visible
    __syncthreads();                      // all lanes' fences done
    if (tid == 0) {
        unsigned* ctr = (unsigned*)(ws + CTR_OFF);
        unsigned old = atomicInc(&ctr[atom], 7u);  // wraps mod 8; 8th sees 6
        last_flag = (old == 6u) ? 1u : 0u;
    }
    __syncthreads();
    if (last_flag) {
        __threadfence();                  // acquire: see other blocks' stores
        if (tid < 128) {
            const int n = tid >> 4, q = tid & 15;
            const float* base = ws + atom*SLABS*128;
            float redk[8];
            #pragma unroll
            for (int k = 0; k < 8; ++k) {
                float sk = 0.0f;
                #pragma unroll
                for (int s2 = 0; s2 < 8; ++s2)
                    sk += base[s2*128 + k*16 + q];
                redk[k] = sk;
            }
            float sum = 0.0f;
            #pragma unroll
            for (int k = 0; k < 8; ++k)
                sum = fmaf(W[n*8+k], redk[k], sum);
            out[atom*128 + tid] = sum * VCELL_F;
        }
    }
}

extern "C" void kernel_launch(void* const* d_in, const int* in_sizes, int n_in,
                              void* d_out, int out_size, void* d_ws, size_t ws_size,
                              hipStream_t stream) {
    const float* rho = (const float*)d_in[0];   // 180^3
    const float* pos = (const float*)d_in[1];   // 64 x 3
    const float* W   = (const float*)d_in[2];   // 8 x 8
    float* out = (float*)d_out;                 // 64 x 128 fp32
    float* ws  = (float*)d_ws;                  // partials + counters

    dim3 grid(SLABS, NATOMS);
    proj_fused_kernel<<<grid, 256, 0, stream>>>(rho, pos, W, out, ws);
}

// Round 4
// 88.849 us; speedup vs baseline: 1.3470x; 1.3470x over previous
//
#include <hip/hip_runtime.h>

// Problem constants (from reference):
//   L=36, G=180, A=0.2, RO=2.5, RMAX=13, B=27, CELLS=27^3=19683
//   NRAD=8, NL=4 -> 16 masked (l,m) pairs, VCELL=0.008
#define G 180
#define NRAD 8
#define RO_F 2.5f
#define A_F 0.2f
#define VCELL_F 0.008f
#define CELLS 19683
#define SLABS 8
#define NATOMS 64

// lm ordering (matches coeff[:, MASK].reshape(-1)):
// 0:(0,0) 1:(1,-1) 2:(1,0) 3:(1,1) 4:(2,-2) 5:(2,-1) 6:(2,0) 7:(2,1) 8:(2,2)
// 9:(3,-3) 10:(3,-2) 11:(3,-1) 12:(3,0) 13:(3,1) 14:(3,2) 15:(3,3)

// Anti-spill decomposition: each of the block's 4 waves owns radial pair
// n = {2w, 2w+1} -> 32 accumulators/thread (fits registers; R3's 128/thread
// spilled: VGPR_Count=88 < needed, kernel went latency-bound at 67us).
// All 4 waves walk the SAME 64 cells per iteration; the 4x-redundant rho
// load is an L1 broadcast, the ~35-op geometry recompute is the price of
// register residency.
//
// ws layout: float partials[NATOMS][SLABS][4 waves][32]  (fully overwritten
// every call -> no zero-init needed, safe vs 0xAA poison).

__global__ __launch_bounds__(256, 4) void proj_kernel(
    const float* __restrict__ rho, const float* __restrict__ pos,
    float* __restrict__ ws)
{
    const int atom = blockIdx.y;
    const int slab = blockIdx.x;
    const int tid  = threadIdx.x;
    const int lane = tid & 63;
    const int w    = tid >> 6;         // wave id = radial group

    const float px = pos[atom*3+0], py = pos[atom*3+1], pz = pos[atom*3+2];
    // cm = round(pos/A); dr = pos - A*cm   (A = 0.2 -> pos*5)
    const float cmx = rintf(px * 5.0f), cmy = rintf(py * 5.0f), cmz = rintf(pz * 5.0f);
    const float drx = px - A_F*cmx, dry = py - A_F*cmy, drz = pz - A_F*cmz;
    const int icx = (int)cmx - 13, icy = (int)cmy - 13, icz = (int)cmz - 13;

    float acc[32];                     // [row(n&1)][16 lm]
    #pragma unroll
    for (int j = 0; j < 32; ++j) acc[j] = 0.0f;

    for (int c = slab*64 + lane; c < CELLS; c += SLABS*64) {
        int i = c / 729;
        int rem = c - i*729;
        int j = rem / 27;
        int k = rem - j*27;
        // periodic wrap: i+icx in [-13, 193]
        int gx = i + icx; gx += (gx < 0) ? G : 0; gx -= (gx >= G) ? G : 0;
        int gy = j + icy; gy += (gy < 0) ? G : 0; gy -= (gy >= G) ? G : 0;
        int gz = k + icz; gz += (gz < 0) ? G : 0; gz -= (gz >= G) ? G : 0;
        float s = rho[(gx*G + gy)*G + gz];

        float x = (float)(i-13)*A_F - drx;
        float y = (float)(j-13)*A_F - dry;
        float z = (float)(k-13)*A_F - drz;
        float r2 = x*x + y*y + z*z;
        float inv = rsqrtf(fmaxf(r2, 1e-24f));
        float R = r2 * inv;                 // == sqrt(r2)
        if (R < RO_F) {
            float t = RO_F - R;
            float ux = x*inv, uy = y*inv, uz = z*inv;
            float uz2 = uz*uz;
            float ux2 = ux*ux, uy2 = uy*uy;
            float ys[16];
            ys[0]  = 0.28209479177f;
            ys[1]  = 0.48860251190f * uy;
            ys[2]  = 0.48860251190f * uz;
            ys[3]  = 0.48860251190f * ux;
            ys[4]  = 1.09254843059f * ux*uy;            // 2 * 0.54627 * ux uy
            ys[5]  = 1.09254843059f * uy*uz;
            ys[6]  = 0.31539156525f * (3.0f*uz2 - 1.0f);
            ys[7]  = 1.09254843059f * ux*uz;
            ys[8]  = 0.54627421530f * (ux2 - uy2);
            ys[9]  = 0.59004358993f * uy*(3.0f*ux2 - uy2);
            ys[10] = 2.89061144264f * ux*uy*uz;         // 2 * 1.44530572
            ys[11] = 0.45704579946f * uy*(5.0f*uz2 - 1.0f);
            ys[12] = 0.37317633259f * uz*(5.0f*uz2 - 3.0f);
            ys[13] = 0.45704579946f * ux*(5.0f*uz2 - 1.0f);
            ys[14] = 1.44530572132f * (ux2 - uy2)*uz;
            ys[15] = 0.59004358993f * ux*(ux2 - 3.0f*uy2);

            // group's first radial: p = s * r2 * t^(2+2w)   (w wave-uniform)
            float t2 = t*t;
            float p = s * r2 * t2;
            if (w >= 1) p *= t2;
            if (w >= 2) p *= t2;
            if (w >= 3) p *= t2;
            float pt = p * t;               // second radial of the pair
            #pragma unroll
            for (int q = 0; q < 16; ++q) {
                acc[q]    = fmaf(p,  ys[q], acc[q]);
                acc[16+q] = fmaf(pt, ys[q], acc[16+q]);
            }
        }
    }

    // Per-wave reduction: LDS pad-33 transpose (2-way bank alias = free),
    // each lane sums a 32-row half-column, combine halves, store partial.
    __shared__ float red[4][64][33];      // ~33.8 KB
    __shared__ float stage[4][2][32];
    #pragma unroll
    for (int q = 0; q < 32; ++q)
        red[w][lane][q] = acc[q];
    __syncthreads();
    const int col  = lane & 31;
    const int half = lane >> 5;
    float csum = 0.0f;
    #pragma unroll
    for (int r = 0; r < 32; ++r)
        csum += red[w][half*32 + r][col];
    stage[w][half][col] = csum;
    __syncthreads();
    if (lane < 32) {
        float v = stage[w][0][lane] + stage[w][1][lane];
        ws[((atom*SLABS + slab)*4 + w)*32 + lane] = v;
    }
}

// out[atom][n*16+q] = VCELL * sum_k W[n][k] * (sum_slab partial[slab][k])
// partial index: group g=k>>1, row=k&1 -> ws[((atom*8+s)*4+g)*32 + row*16+q]
__global__ void finalize_kernel(const float* __restrict__ ws,
                                const float* __restrict__ W,
                                float* __restrict__ out)
{
    const int atom = blockIdx.x;
    const int t = threadIdx.x;        // 128 threads
    const int n = t >> 4, q = t & 15;
    const float* base = ws + atom*SLABS*4*32;
    float M[8];
    #pragma unroll
    for (int k = 0; k < 8; ++k) {
        const int g = k >> 1, row = k & 1;
        float sk = 0.0f;
        #pragma unroll
        for (int s = 0; s < 8; ++s)
            sk += base[(s*4 + g)*32 + row*16 + q];
        M[k] = sk;
    }
    float sum = 0.0f;
    #pragma unroll
    for (int k = 0; k < 8; ++k)
        sum = fmaf(W[n*8+k], M[k], sum);
    out[atom*128 + t] = sum * VCELL_F;
}

extern "C" void kernel_launch(void* const* d_in, const int* in_sizes, int n_in,
                              void* d_out, int out_size, void* d_ws, size_t ws_size,
                              hipStream_t stream) {
    const float* rho = (const float*)d_in[0];   // 180^3
    const float* pos = (const float*)d_in[1];   // 64 x 3
    const float* W   = (const float*)d_in[2];   // 8 x 8
    float* out = (float*)d_out;                 // 64 x 128 fp32
    float* ws  = (float*)d_ws;                  // 64*8*4*32 fp32 partials

    dim3 grid(SLABS, NATOMS);
    proj_kernel<<<grid, 256, 0, stream>>>(rho, pos, ws);
    finalize_kernel<<<NATOMS, 128, 0, stream>>>(ws, W, out);
}

// Round 5
// 80.226 us; speedup vs baseline: 1.4918x; 1.1075x over previous
//
#include <hip/hip_runtime.h>

// Problem constants (from reference):
//   L=36, G=180, A=0.2, RO=2.5, RMAX=13, B=27, CELLS=27^3=19683
//   NRAD=8, NL=4 -> 16 masked (l,m) pairs, VCELL=0.008
#define G 180
#define NRAD 8
#define RO_F 2.5f
#define A_F 0.2f
#define VCELL_F 0.008f
#define CELLS 19683
#define SLABS 16
#define NATOMS 64
#define ITERS 10          // ceil(19683 / (SLABS*128)) with guard-by-geometry

// lm ordering (matches coeff[:, MASK].reshape(-1)):
// 0:(0,0) 1:(1,-1) 2:(1,0) 3:(1,1) 4:(2,-2) 5:(2,-1) 6:(2,0) 7:(2,1) 8:(2,2)
// 9:(3,-3) 10:(3,-2) 11:(3,-1) 12:(3,0) 13:(3,1) 14:(3,2) 15:(3,3)
//
// Decomposition (R4 post-mortem: minimize redundancy x iterations x latency):
//   wave w: radial group g=w>>1 (radials 4g..4g+3), cell subgroup cw=w&1.
//   -> acc[64]/thread (fits VGPRs under launch_bounds(256,3) cap ~168),
//      2x geometry redundancy (vs R4's 4x), 128 distinct cells/block/iter,
//      10 iterations with explicit rho prefetch to hide gather latency.
// Out-of-range padded cells (c>=CELLS) have i>=27 -> x>=2.7>RO -> skipped by
// the R<RO test; wrapped index stays in [0,G) so the load is always safe.
//
// ws layout: float partials[NATOMS][SLABS][4 waves][64] (1 MB, fully
// overwritten every call -> no zero-init, safe vs 0xAA poison).

__global__ __launch_bounds__(256, 3) void proj_kernel(
    const float* __restrict__ rho, const float* __restrict__ pos,
    float* __restrict__ ws)
{
    const int atom = blockIdx.y;
    const int slab = blockIdx.x;
    const int tid  = threadIdx.x;
    const int lane = tid & 63;
    const int w    = tid >> 6;
    const int g    = w >> 1;          // radial group: n = 4g..4g+3
    const int cw   = w & 1;           // cell subgroup

    const float px = pos[atom*3+0], py = pos[atom*3+1], pz = pos[atom*3+2];
    // cm = round(pos/A); dr = pos - A*cm   (A = 0.2 -> pos*5)
    const float cmx = rintf(px * 5.0f), cmy = rintf(py * 5.0f), cmz = rintf(pz * 5.0f);
    const float drx = px - A_F*cmx, dry = py - A_F*cmy, drz = pz - A_F*cmz;
    const int icx = (int)cmx - 13, icy = (int)cmy - 13, icz = (int)cmz - 13;

    float acc[64];
    #pragma unroll
    for (int j = 0; j < 64; ++j) acc[j] = 0.0f;

    int c = slab*128 + cw*64 + lane;

    // prefetch cell 0
    int i_n, j_n, k_n; float s_n;
    {
        int i = c / 729; int rem = c - i*729; int j = rem / 27; int k = rem - j*27;
        int gx = i + icx; gx += (gx < 0) ? G : 0; gx -= (gx >= G) ? G : 0;
        int gy = j + icy; gy += (gy < 0) ? G : 0; gy -= (gy >= G) ? G : 0;
        int gz = k + icz; gz += (gz < 0) ? G : 0; gz -= (gz >= G) ? G : 0;
        i_n = i; j_n = j; k_n = k;
        s_n = rho[(gx*G + gy)*G + gz];
    }

    for (int it = 0; it < ITERS; ++it) {
        const int i = i_n, j = j_n, k = k_n;
        const float s = s_n;
        c += SLABS*128;
        if (it != ITERS-1) {        // prefetch next cell (overlaps compute)
            int i2 = c / 729; int rem = c - i2*729; int j2 = rem / 27; int k2 = rem - j2*27;
            int gx = i2 + icx; gx += (gx < 0) ? G : 0; gx -= (gx >= G) ? G : 0;
            int gy = j2 + icy; gy += (gy < 0) ? G : 0; gy -= (gy >= G) ? G : 0;
            int gz = k2 + icz; gz += (gz < 0) ? G : 0; gz -= (gz >= G) ? G : 0;
            i_n = i2; j_n = j2; k_n = k2;
            s_n = rho[(gx*G + gy)*G + gz];
        }

        float x = (float)(i-13)*A_F - drx;
        float y = (float)(j-13)*A_F - dry;
        float z = (float)(k-13)*A_F - drz;
        float r2 = x*x + y*y + z*z;
        float inv = rsqrtf(fmaxf(r2, 1e-24f));
        float R = r2 * inv;                 // == sqrt(r2)
        if (R < RO_F) {
            float t = RO_F - R;
            float ux = x*inv, uy = y*inv, uz = z*inv;
            float uz2 = uz*uz;
            float ux2 = ux*ux, uy2 = uy*uy;
            float ys[16];
            ys[0]  = 0.28209479177f;
            ys[1]  = 0.48860251190f * uy;
            ys[2]  = 0.48860251190f * uz;
            ys[3]  = 0.48860251190f * ux;
            ys[4]  = 1.09254843059f * ux*uy;            // 2 * 0.54627 * ux uy
            ys[5]  = 1.09254843059f * uy*uz;
            ys[6]  = 0.31539156525f * (3.0f*uz2 - 1.0f);
            ys[7]  = 1.09254843059f * ux*uz;
            ys[8]  = 0.54627421530f * (ux2 - uy2);
            ys[9]  = 0.59004358993f * uy*(3.0f*ux2 - uy2);
            ys[10] = 2.89061144264f * ux*uy*uz;         // 2 * 1.44530572
            ys[11] = 0.45704579946f * uy*(5.0f*uz2 - 1.0f);
            ys[12] = 0.37317633259f * uz*(5.0f*uz2 - 3.0f);
            ys[13] = 0.45704579946f * ux*(5.0f*uz2 - 1.0f);
            ys[14] = 1.44530572132f * (ux2 - uy2)*uz;
            ys[15] = 0.59004358993f * ux*(ux2 - 3.0f*uy2);

            // group's first radial: p0 = s * r2 * t^(2+4g)   (g wave-uniform)
            float t2 = t*t;
            float p0 = s * r2 * t2;
            if (g) { float t4 = t2*t2; p0 *= t4; }
            float p1 = p0*t, p2 = p1*t, p3 = p2*t;
            #pragma unroll
            for (int q = 0; q < 16; ++q) {
                acc[q]    = fmaf(p0, ys[q], acc[q]);
                acc[16+q] = fmaf(p1, ys[q], acc[16+q]);
                acc[32+q] = fmaf(p2, ys[q], acc[32+q]);
                acc[48+q] = fmaf(p3, ys[q], acc[48+q]);
            }
        }
    }

    // Wave-local reduction (each wave owns red[w]/stage[w] -> NO barriers).
    // Pad-33 transpose: write banks (lane+q)&31 2-way alias (free, m136);
    // read banks (33r+col)&31 2-way across halves (free).
    __shared__ float red[4][64][33];      // ~33.8 KB
    __shared__ float stage[4][2][32];
    const int col  = lane & 31;
    const int half = lane >> 5;
    #pragma unroll
    for (int ch = 0; ch < 2; ++ch) {
        #pragma unroll
        for (int q = 0; q < 32; ++q)
            red[w][lane][q] = acc[ch*32 + q];
        float csum = 0.0f;
        #pragma unroll
        for (int r = 0; r < 32; ++r)
            csum += red[w][half*32 + r][col];
        stage[w][half][col] = csum;
        if (lane < 32) {
            float v = stage[w][0][lane] + stage[w][1][lane];
            ws[((atom*SLABS + slab)*4 + w)*64 + ch*32 + lane] = v;
        }
    }
}

// out[atom][n*16+q] = VCELL * sum_k W[n][k] * M[k][q]
// M[k][q] = sum over slab(16) x cw(2) of ws[((atom*16+s)*4 + (k>>2)*2+cw)*64
//                                          + (k&3)*16 + q]
__global__ void finalize_kernel(const float* __restrict__ ws,
                                const float* __restrict__ W,
                                float* __restrict__ out)
{
    const int atom = blockIdx.x;
    const int t = threadIdx.x;        // 128 threads
    const int n = t >> 4, q = t & 15;
    const int g = n >> 2, r = n & 3;
    const float* base = ws + atom*SLABS*4*64;
    float m = 0.0f;
    #pragma unroll
    for (int s = 0; s < SLABS; ++s) {
        m += base[(s*4 + g*2 + 0)*64 + r*16 + q];
        m += base[(s*4 + g*2 + 1)*64 + r*16 + q];
    }
    __shared__ float M[8][16];
    M[n][q] = m;
    __syncthreads();
    float sum = 0.0f;
    #pragma unroll
    for (int k = 0; k < 8; ++k)
        sum = fmaf(W[n*8+k], M[k][q], sum);
    out[atom*128 + t] = sum * VCELL_F;
}

extern "C" void kernel_launch(void* const* d_in, const int* in_sizes, int n_in,
                              void* d_out, int out_size, void* d_ws, size_t ws_size,
                              hipStream_t stream) {
    const float* rho = (const float*)d_in[0];   // 180^3
    const float* pos = (const float*)d_in[1];   // 64 x 3
    const float* W   = (const float*)d_in[2];   // 8 x 8
    float* out = (float*)d_out;                 // 64 x 128 fp32
    float* ws  = (float*)d_ws;                  // 64*16*4*64 fp32 partials

    dim3 grid(SLABS, NATOMS);
    proj_kernel<<<grid, 256, 0, stream>>>(rho, pos, ws);
    finalize_kernel<<<NATOMS, 128, 0, stream>>>(ws, W, out);
}